// Round 1
// baseline (455.297 us; speedup 1.0000x reference)
//
#include <hip/hip_runtime.h>
#include <stdint.h>

#define BATCH 4
#define CH 64
#define HW 80
#define NPIX 6400

typedef __attribute__((ext_vector_type(8))) short bf16x8;
typedef __attribute__((ext_vector_type(4))) float f32x4;

static __device__ __forceinline__ unsigned short f2bf(float f) {
  union { float f; unsigned int u; } v; v.f = f;
  unsigned int u = v.u;
  unsigned int r = (u + 0x7fffu + ((u >> 16) & 1u)) >> 16;
  return (unsigned short)r;
}

// ---------------- QKV 1x1 conv ----------------
// writes: Qbf [B][N][C] bf16 (keys, row-major pixels)
//         Qtbf[B][N][C] bf16 (queries: row p = Q[t(p)])
//         VtTbf[B][C][N] bf16 (VtT[c][n] = v[c][t(n)])
//         K32 [B][C][N] f32, Qt32[B][C][N] f32 (Qt32[c][n]=q[c][t(n)]), V32 [B][C][N] f32
__global__ __launch_bounds__(256) void qkv_kernel(
    const float* __restrict__ x, const float* __restrict__ w,
    const float* __restrict__ bias,
    unsigned short* __restrict__ Qbf, unsigned short* __restrict__ Qtbf,
    unsigned short* __restrict__ VtTbf, float* __restrict__ K32,
    float* __restrict__ Qt32, float* __restrict__ V32) {
  int bid = blockIdx.x;
  int b = bid / 100, tile = bid % 100;
  int p0 = tile * 64;
  int t = threadIdx.x;
  int i = t & 63;
  int og = __builtin_amdgcn_readfirstlane(t >> 6);  // wave-uniform -> s_loads for W
  int p = p0 + i;
  int tp = (p % HW) * HW + p / HW;
  const float* xb = x + (size_t)b * CH * NPIX + p;
  float xv[64];
#pragma unroll
  for (int c = 0; c < 64; ++c) xv[c] = xb[(size_t)c * NPIX];
  size_t bq = (size_t)b * NPIX;
  size_t bc = (size_t)b * CH * NPIX;
  for (int j = 0; j < 48; ++j) {
    int o = og * 48 + j;
    const float* wr = w + o * 64;
    float a = bias[o];
#pragma unroll
    for (int c = 0; c < 64; ++c) a += wr[c] * xv[c];
    int cc = o & 63;
    int kind = o >> 6;
    if (kind == 0) {
      Qbf[(bq + p) * 64 + cc] = f2bf(a);
      Qtbf[(bq + tp) * 64 + cc] = f2bf(a);
      Qt32[bc + (size_t)cc * NPIX + tp] = a;
    } else if (kind == 1) {
      K32[bc + (size_t)cc * NPIX + p] = a;
    } else {
      V32[bc + (size_t)cc * NPIX + p] = a;
      VtTbf[bc + (size_t)cc * NPIX + tp] = f2bf(a);
    }
  }
}

// ---------------- channel gram: M[c][c'] = sum_n K32[c][n]*Qt32[c'][n] ----------------
__global__ __launch_bounds__(256) void gram_kernel(
    const float* __restrict__ K32, const float* __restrict__ Qt32,
    float* __restrict__ PcLog) {
  __shared__ float Ks[64][65];
  __shared__ float Qs[64][65];
  int bid = blockIdx.x;
  int b = bid / 100, nt = bid % 100;
  int n0 = nt * 64;
  int t = threadIdx.x;
  int col = t & 63, rg = t >> 6;
  size_t base = (size_t)b * CH * NPIX + n0 + col;
#pragma unroll
  for (int r = 0; r < 16; ++r) {
    int row = rg * 16 + r;
    Ks[row][col] = K32[base + (size_t)row * NPIX];
    Qs[row][col] = Qt32[base + (size_t)row * NPIX];
  }
  __syncthreads();
  float acc[16];
#pragma unroll
  for (int jj = 0; jj < 16; ++jj) acc[jj] = 0.f;
  for (int nn = 0; nn < 64; ++nn) {
    float kv = Ks[col][nn];
#pragma unroll
    for (int jj = 0; jj < 16; ++jj) acc[jj] += kv * Qs[rg * 16 + jj][nn];
  }
  float* dst = PcLog + ((size_t)b * 64 + col) * 64 + rg * 16;
#pragma unroll
  for (int jj = 0; jj < 16; ++jj) atomicAdd(&dst[jj], acc[jj]);
}

// softmax rows of Pc (in place) + write transpose PcT
__global__ __launch_bounds__(256) void gram_softmax(float* __restrict__ Pc,
                                                    float* __restrict__ PcT) {
  int t = threadIdx.x;
  int b = t >> 6, c = t & 63;
  float* row = Pc + ((size_t)b * 64 + c) * 64;
  float v[64];
  float mx = -1e30f;
#pragma unroll
  for (int j = 0; j < 64; ++j) { v[j] = row[j]; mx = fmaxf(mx, v[j]); }
  float s = 0.f;
#pragma unroll
  for (int j = 0; j < 64; ++j) { v[j] = __expf(v[j] - mx); s += v[j]; }
  float inv = 1.f / s;
#pragma unroll
  for (int j = 0; j < 64; ++j) {
    float pv = v[j] * inv;
    row[j] = pv;
    PcT[((size_t)b * 64 + j) * 64 + c] = pv;
  }
}

// out[b][c][n] = sum_c' ma[c][c'] * v[c'][n]   (writes out, flash then +=)
__global__ __launch_bounds__(256) void chan_apply(
    const float* __restrict__ PcT, const float* __restrict__ V32,
    float* __restrict__ out) {
  int bid = blockIdx.x;
  int b = bid / 25, nt = bid % 25;
  int n = nt * 256 + threadIdx.x;
  size_t bc = (size_t)b * CH * NPIX;
  float acc[64];
#pragma unroll
  for (int c = 0; c < 64; ++c) acc[c] = 0.f;
  for (int cp = 0; cp < 64; ++cp) {
    float vv = V32[bc + (size_t)cp * NPIX + n];
    const float* prow = PcT + ((size_t)b * 64 + cp) * 64;
#pragma unroll
    for (int c = 0; c < 64; ++c) acc[c] += prow[c] * vv;
  }
#pragma unroll
  for (int c = 0; c < 64; ++c) out[bc + (size_t)c * NPIX + n] = acc[c];
}

// ---------------- flash spatial attention ----------------
// block: 64 output pixels p in [p0,p0+64); wave w owns 16 query rows.
// O[p][c] = sum_n' softmax(Q[t(p)]·Q[n'])[n'] * V[t(n')][c];  out[b][c][p] += O[p][c]
__global__ __launch_bounds__(256) void flash_kernel(
    const unsigned short* __restrict__ Qbf,
    const unsigned short* __restrict__ Qtbf,
    const unsigned short* __restrict__ VtTbf, float* __restrict__ out) {
  __shared__ char smem[36864] __attribute__((aligned(128)));
  unsigned short* Qs = (unsigned short*)smem;            // [64][72]
  unsigned short* Ks = (unsigned short*)(smem + 9216);   // [64][72]
  unsigned short* Vs = (unsigned short*)(smem + 18432);  // [64][72]  (c rows, key cols)
  unsigned short* Pb = (unsigned short*)(smem + 27648);  // [4][16][72]
  float* Obuf = (float*)(smem + 9216);                   // [64][65] epilogue (aliases Ks/Vs)

  int bid = blockIdx.x;
  int b = bid / 100, pt = bid % 100;
  int p0 = pt * 64;
  int t = threadIdx.x;
  int w = t >> 6, lane = t & 63;
  int quad = lane >> 4, l16 = lane & 15;

  const unsigned short* Qt_base = Qtbf + ((size_t)b * NPIX + p0) * 64;
#pragma unroll
  for (int rep = 0; rep < 2; ++rep) {
    int ch = t + rep * 256;
    int r = ch >> 3, s = ch & 7;
    *(uint4*)&Qs[r * 72 + s * 8] = *(const uint4*)&Qt_base[r * 64 + s * 8];
  }
  __syncthreads();
  bf16x8 aq[2];
#pragma unroll
  for (int ks = 0; ks < 2; ++ks)
    aq[ks] = *(const bf16x8*)&Qs[(w * 16 + l16) * 72 + ks * 32 + quad * 8];

  f32x4 oacc[4];
#pragma unroll
  for (int ct = 0; ct < 4; ++ct) oacc[ct] = (f32x4){0.f, 0.f, 0.f, 0.f};
  float mrun[4], lrun[4];
#pragma unroll
  for (int r = 0; r < 4; ++r) { mrun[r] = -1e30f; lrun[r] = 0.f; }

  const unsigned short* Kb_base = Qbf + (size_t)b * NPIX * 64;
  const unsigned short* Vb_base = VtTbf + (size_t)b * CH * NPIX;

  for (int kt = 0; kt < 100; ++kt) {
    int n0 = kt * 64;
    __syncthreads();  // previous iter's Ks/Vs reads done
#pragma unroll
    for (int rep = 0; rep < 2; ++rep) {
      int ch = t + rep * 256;
      int r = ch >> 3, s = ch & 7;
      *(uint4*)&Ks[r * 72 + s * 8] =
          *(const uint4*)&Kb_base[((size_t)(n0 + r)) * 64 + s * 8];
      *(uint4*)&Vs[r * 72 + s * 8] =
          *(const uint4*)&Vb_base[(size_t)r * NPIX + n0 + s * 8];
    }
    __syncthreads();
    // scores S[16 x 64] per wave
    f32x4 sc[4];
#pragma unroll
    for (int ct = 0; ct < 4; ++ct) {
      sc[ct] = (f32x4){0.f, 0.f, 0.f, 0.f};
#pragma unroll
      for (int ks = 0; ks < 2; ++ks) {
        bf16x8 bk = *(const bf16x8*)&Ks[(ct * 16 + l16) * 72 + ks * 32 + quad * 8];
        sc[ct] = __builtin_amdgcn_mfma_f32_16x16x32_bf16(aq[ks], bk, sc[ct], 0, 0, 0);
      }
    }
    // online softmax: lane's reg r is row quad*4+r, col ct*16+l16
    float mnew[4], alpha[4];
#pragma unroll
    for (int r = 0; r < 4; ++r) {
      float mx = fmaxf(fmaxf(sc[0][r], sc[1][r]), fmaxf(sc[2][r], sc[3][r]));
#pragma unroll
      for (int off = 1; off < 16; off <<= 1) mx = fmaxf(mx, __shfl_xor(mx, off, 64));
      mnew[r] = fmaxf(mrun[r], mx);
      alpha[r] = __expf(mrun[r] - mnew[r]);
    }
#pragma unroll
    for (int ct = 0; ct < 4; ++ct)
#pragma unroll
      for (int r = 0; r < 4; ++r) sc[ct][r] = __expf(sc[ct][r] - mnew[r]);
#pragma unroll
    for (int r = 0; r < 4; ++r) {
      float sm = sc[0][r] + sc[1][r] + sc[2][r] + sc[3][r];
#pragma unroll
      for (int off = 1; off < 16; off <<= 1) sm += __shfl_xor(sm, off, 64);
      lrun[r] = lrun[r] * alpha[r] + sm;
      mrun[r] = mnew[r];
    }
#pragma unroll
    for (int ct = 0; ct < 4; ++ct)
#pragma unroll
      for (int r = 0; r < 4; ++r) oacc[ct][r] *= alpha[r];
    // P (C-layout) -> LDS -> A-layout frags
    unsigned short* Pw = Pb + w * 16 * 72;
#pragma unroll
    for (int ct = 0; ct < 4; ++ct)
#pragma unroll
      for (int r = 0; r < 4; ++r)
        Pw[(quad * 4 + r) * 72 + ct * 16 + l16] = f2bf(sc[ct][r]);
    __syncthreads();
    bf16x8 pf[2];
#pragma unroll
    for (int ks = 0; ks < 2; ++ks)
      pf[ks] = *(const bf16x8*)&Pw[l16 * 72 + ks * 32 + quad * 8];
#pragma unroll
    for (int ct = 0; ct < 4; ++ct)
#pragma unroll
      for (int ks = 0; ks < 2; ++ks) {
        bf16x8 vf = *(const bf16x8*)&Vs[(ct * 16 + l16) * 72 + ks * 32 + quad * 8];
        oacc[ct] = __builtin_amdgcn_mfma_f32_16x16x32_bf16(pf[ks], vf, oacc[ct], 0, 0, 0);
      }
  }
  __syncthreads();
  float inv[4];
#pragma unroll
  for (int r = 0; r < 4; ++r) inv[r] = 1.f / lrun[r];
#pragma unroll
  for (int ct = 0; ct < 4; ++ct)
#pragma unroll
    for (int r = 0; r < 4; ++r)
      Obuf[(w * 16 + quad * 4 + r) * 65 + ct * 16 + l16] = oacc[ct][r] * inv[r];
  __syncthreads();
  float* ob = out + (size_t)b * CH * NPIX + p0;
#pragma unroll
  for (int rep = 0; rep < 16; ++rep) {
    int idx = t + rep * 256;
    int c = idx >> 6, pp = idx & 63;
    ob[(size_t)c * NPIX + pp] += Obuf[pp * 65 + c];
  }
}

extern "C" void kernel_launch(void* const* d_in, const int* in_sizes, int n_in,
                              void* d_out, int out_size, void* d_ws, size_t ws_size,
                              hipStream_t stream) {
  const float* x = (const float*)d_in[0];
  const float* w = (const float*)d_in[1];
  const float* bias = (const float*)d_in[2];
  float* out = (float*)d_out;
  char* ws = (char*)d_ws;
  // workspace layout (bytes)
  unsigned short* Qbf = (unsigned short*)(ws);              // 3,276,800
  unsigned short* Qtbf = (unsigned short*)(ws + 3276800);   // 3,276,800
  unsigned short* VtTbf = (unsigned short*)(ws + 6553600);  // 3,276,800
  float* K32 = (float*)(ws + 9830400);                      // 6,553,600
  float* Qt32 = (float*)(ws + 16384000);                    // 6,553,600
  float* V32 = (float*)(ws + 22937600);                     // 6,553,600
  float* Pc = (float*)(ws + 29491200);                      // 65,536
  float* PcT = (float*)(ws + 29556736);                     // 65,536  (total ~28.3 MB)

  hipMemsetAsync(Pc, 0, 65536, stream);
  qkv_kernel<<<400, 256, 0, stream>>>(x, w, bias, Qbf, Qtbf, VtTbf, K32, Qt32, V32);
  gram_kernel<<<400, 256, 0, stream>>>(K32, Qt32, Pc);
  gram_softmax<<<1, 256, 0, stream>>>(Pc, PcT);
  chan_apply<<<100, 256, 0, stream>>>(PcT, V32, out);
  flash_kernel<<<400, 256, 0, stream>>>(Qbf, Qtbf, VtTbf, out);
}

// Round 2
// 295.338 us; speedup vs baseline: 1.5416x; 1.5416x over previous
//
#include <hip/hip_runtime.h>
#include <stdint.h>

#define BATCH 4
#define CH 64
#define HW 80
#define NPIX 6400

typedef __attribute__((ext_vector_type(8))) short bf16x8;
typedef __attribute__((ext_vector_type(4))) float f32x4;

static __device__ __forceinline__ unsigned short f2bf(float f) {
  union { float f; unsigned int u; } v; v.f = f;
  unsigned int u = v.u;
  unsigned int r = (u + 0x7fffu + ((u >> 16) & 1u)) >> 16;
  return (unsigned short)r;
}

// ---------------- QKV 1x1 conv ----------------
__global__ __launch_bounds__(256) void qkv_kernel(
    const float* __restrict__ x, const float* __restrict__ w,
    const float* __restrict__ bias,
    unsigned short* __restrict__ Qbf, unsigned short* __restrict__ Qtbf,
    unsigned short* __restrict__ VtTbf, float* __restrict__ K32,
    float* __restrict__ Qt32, float* __restrict__ V32) {
  int bid = blockIdx.x;
  int b = bid / 100, tile = bid % 100;
  int p0 = tile * 64;
  int t = threadIdx.x;
  int i = t & 63;
  int og = __builtin_amdgcn_readfirstlane(t >> 6);
  int p = p0 + i;
  int tp = (p % HW) * HW + p / HW;
  const float* xb = x + (size_t)b * CH * NPIX + p;
  float xv[64];
#pragma unroll
  for (int c = 0; c < 64; ++c) xv[c] = xb[(size_t)c * NPIX];
  size_t bq = (size_t)b * NPIX;
  size_t bc = (size_t)b * CH * NPIX;
  for (int j = 0; j < 48; ++j) {
    int o = og * 48 + j;
    const float* wr = w + o * 64;
    float a = bias[o];
#pragma unroll
    for (int c = 0; c < 64; ++c) a += wr[c] * xv[c];
    int cc = o & 63;
    int kind = o >> 6;
    if (kind == 0) {
      Qbf[(bq + p) * 64 + cc] = f2bf(a);
      Qtbf[(bq + tp) * 64 + cc] = f2bf(a);
      Qt32[bc + (size_t)cc * NPIX + tp] = a;
    } else if (kind == 1) {
      K32[bc + (size_t)cc * NPIX + p] = a;
    } else {
      V32[bc + (size_t)cc * NPIX + p] = a;
      VtTbf[bc + (size_t)cc * NPIX + tp] = f2bf(a);
    }
  }
}

// ---------------- channel gram: Pc[c][c'] = sum_n K32[c][n]*Qt32[c'][n] ----------------
__global__ __launch_bounds__(256) void gram_kernel(
    const float* __restrict__ K32, const float* __restrict__ Qt32,
    float* __restrict__ PcLog) {
  __shared__ float Ks[64][65];
  __shared__ float Qs[64][65];
  int bid = blockIdx.x;
  int b = bid / 25, chunk = bid % 25;
  int t = threadIdx.x;
  int col = t & 63, rg = t >> 6;
  float acc[16];
#pragma unroll
  for (int jj = 0; jj < 16; ++jj) acc[jj] = 0.f;
  for (int sub = 0; sub < 4; ++sub) {
    int n0 = (chunk * 4 + sub) * 64;
    size_t base = (size_t)b * CH * NPIX + n0 + col;
    __syncthreads();
#pragma unroll
    for (int r = 0; r < 16; ++r) {
      int row = rg * 16 + r;
      Ks[row][col] = K32[base + (size_t)row * NPIX];
      Qs[row][col] = Qt32[base + (size_t)row * NPIX];
    }
    __syncthreads();
    for (int nn = 0; nn < 64; ++nn) {
      float kv = Ks[col][nn];
#pragma unroll
      for (int jj = 0; jj < 16; ++jj) acc[jj] += kv * Qs[rg * 16 + jj][nn];
    }
  }
  float* dst = PcLog + ((size_t)b * 64 + col) * 64 + rg * 16;
#pragma unroll
  for (int jj = 0; jj < 16; ++jj) atomicAdd(&dst[jj], acc[jj]);
}

// ---------------- channel apply (softmax fused): out[b][c][n] = sum_c' ma[c][c']*v[c'][n]
__global__ __launch_bounds__(256) void chan_apply(
    const float* __restrict__ Pc, const float* __restrict__ V32,
    float* __restrict__ out) {
  __shared__ float maT[64 * 64];  // [cp][c] = ma[c][cp]
  int bid = blockIdx.x;
  int b = bid / 25, nt = bid % 25;
  int t = threadIdx.x;
  if (t < 64) {
    int c = t;
    const float* row = Pc + ((size_t)b * 64 + c) * 64;
    float v[64];
    float mx = -1e30f;
#pragma unroll
    for (int j = 0; j < 64; ++j) { v[j] = row[j]; mx = fmaxf(mx, v[j]); }
    float s = 0.f;
#pragma unroll
    for (int j = 0; j < 64; ++j) { v[j] = __expf(v[j] - mx); s += v[j]; }
    float inv = 1.f / s;
#pragma unroll
    for (int j = 0; j < 64; ++j) maT[j * 64 + c] = v[j] * inv;
  }
  __syncthreads();
  int n = nt * 256 + t;
  size_t bc = (size_t)b * CH * NPIX;
  float acc[64];
#pragma unroll
  for (int c = 0; c < 64; ++c) acc[c] = 0.f;
  for (int cp = 0; cp < 64; ++cp) {
    float vv = V32[bc + (size_t)cp * NPIX + n];
#pragma unroll
    for (int c = 0; c < 64; ++c) acc[c] += maT[cp * 64 + c] * vv;
  }
#pragma unroll
  for (int c = 0; c < 64; ++c) out[bc + (size_t)c * NPIX + n] = acc[c];
}

// ---------------- flash spatial attention, split-K, no-max softmax ----------------
// grid 1000 = 4b x 50 qtiles(128 rows) x 5 splits. Wave owns 32 query rows.
// Computes S^T via mfma(K-rows, Q-rows); P packs as consecutive-k b64 writes;
// PV via mfma(V^T-rows, P-rows) -> O^T[c][m] -> coalesced atomics into Oacc[b][c][p].
__global__ __launch_bounds__(256) void flash_kernel(
    const unsigned short* __restrict__ Qbf,    // keys   [b][n][c]
    const unsigned short* __restrict__ Qtbf,   // query  [b][p][c]
    const unsigned short* __restrict__ VtTbf,  // V^T    [b][c][n]
    float* __restrict__ Oacc,                  // [b][c][p] (pre-zeroed)
    float* __restrict__ Lsum) {                // [b][p]    (pre-zeroed)
  __shared__ char smem[36864] __attribute__((aligned(128)));
  unsigned short* Ks = (unsigned short*)smem;            // [64][72]
  unsigned short* Vs = (unsigned short*)(smem + 9216);   // [64][72]
  unsigned short* Pb = (unsigned short*)(smem + 18432);  // [4 waves][32][72]

  int bid = blockIdx.x;
  int b = bid / 250;
  int rem = bid % 250;
  int qt = rem / 5, split = rem % 5;
  int p0 = qt * 128;
  int t = threadIdx.x;
  int w = t >> 6, lane = t & 63;
  int quad = lane >> 4, l16 = lane & 15;
  size_t bq = (size_t)b * NPIX;
  size_t bC = (size_t)b * CH * NPIX;

  // Q fragments (B operand): rows p0 + w*32 + mr*16 + l16
  bf16x8 aq[2][2];
#pragma unroll
  for (int mr = 0; mr < 2; ++mr)
#pragma unroll
    for (int ks = 0; ks < 2; ++ks)
      aq[mr][ks] = *(const bf16x8*)&Qtbf[(bq + p0 + w * 32 + mr * 16 + l16) * 64 +
                                         ks * 32 + quad * 8];

  f32x4 oacc[2][4];
#pragma unroll
  for (int mr = 0; mr < 2; ++mr)
#pragma unroll
    for (int ct = 0; ct < 4; ++ct) oacc[mr][ct] = (f32x4){0.f, 0.f, 0.f, 0.f};
  float psum[2] = {0.f, 0.f};

  unsigned short* Pw = Pb + w * 32 * 72;
  int kt0 = split * 20;
  for (int kt = kt0; kt < kt0 + 20; ++kt) {
    int n0 = kt * 64;
    __syncthreads();  // prior iter's Ks/Vs reads done
#pragma unroll
    for (int rep = 0; rep < 2; ++rep) {
      int ch = t + rep * 256;
      int r = ch >> 3, s = ch & 7;
      *(uint4*)&Ks[r * 72 + s * 8] = *(const uint4*)&Qbf[(bq + n0 + r) * 64 + s * 8];
      *(uint4*)&Vs[r * 72 + s * 8] = *(const uint4*)&VtTbf[bC + (size_t)r * NPIX + n0 + s * 8];
    }
    __syncthreads();
    // S^T[k][m] = K[k] . Q[m]   (C-layout: row=key=quad*4+r(+16ct), col=query=l16)
    f32x4 sc[2][4];
#pragma unroll
    for (int mr = 0; mr < 2; ++mr)
#pragma unroll
      for (int ct = 0; ct < 4; ++ct) sc[mr][ct] = (f32x4){0.f, 0.f, 0.f, 0.f};
#pragma unroll
    for (int ks = 0; ks < 2; ++ks)
#pragma unroll
      for (int ct = 0; ct < 4; ++ct) {
        bf16x8 bk = *(const bf16x8*)&Ks[(ct * 16 + l16) * 72 + ks * 32 + quad * 8];
        sc[0][ct] = __builtin_amdgcn_mfma_f32_16x16x32_bf16(bk, aq[0][ks], sc[0][ct], 0, 0, 0);
        sc[1][ct] = __builtin_amdgcn_mfma_f32_16x16x32_bf16(bk, aq[1][ks], sc[1][ct], 0, 0, 0);
      }
    // fixed-shift exp; pack consecutive-k bf16 pairs; P stored [m][k] row-major
#pragma unroll
    for (int mr = 0; mr < 2; ++mr)
#pragma unroll
      for (int ct = 0; ct < 4; ++ct) {
        float e0 = __expf(sc[mr][ct][0] - 80.f);
        float e1 = __expf(sc[mr][ct][1] - 80.f);
        float e2 = __expf(sc[mr][ct][2] - 80.f);
        float e3 = __expf(sc[mr][ct][3] - 80.f);
        psum[mr] += (e0 + e1) + (e2 + e3);
        uint2 pk;
        pk.x = (unsigned int)f2bf(e0) | ((unsigned int)f2bf(e1) << 16);
        pk.y = (unsigned int)f2bf(e2) | ((unsigned int)f2bf(e3) << 16);
        *(uint2*)&Pw[(mr * 16 + l16) * 72 + ct * 16 + quad * 4] = pk;
      }
    // PV: O^T[c][m] += V^T[c] . P[m]
    bf16x8 pf0[2], pf1[2];
#pragma unroll
    for (int ks = 0; ks < 2; ++ks) {
      pf0[ks] = *(const bf16x8*)&Pw[(0 * 16 + l16) * 72 + ks * 32 + quad * 8];
      pf1[ks] = *(const bf16x8*)&Pw[(1 * 16 + l16) * 72 + ks * 32 + quad * 8];
    }
#pragma unroll
    for (int ks = 0; ks < 2; ++ks)
#pragma unroll
      for (int ct = 0; ct < 4; ++ct) {
        bf16x8 vf = *(const bf16x8*)&Vs[(ct * 16 + l16) * 72 + ks * 32 + quad * 8];
        oacc[0][ct] = __builtin_amdgcn_mfma_f32_16x16x32_bf16(vf, pf0[ks], oacc[0][ct], 0, 0, 0);
        oacc[1][ct] = __builtin_amdgcn_mfma_f32_16x16x32_bf16(vf, pf1[ks], oacc[1][ct], 0, 0, 0);
      }
  }
  // epilogue: Lsum partial (reduce across quads), Oacc atomics (coalesced in p)
#pragma unroll
  for (int mr = 0; mr < 2; ++mr) {
    float s = psum[mr];
    s += __shfl_xor(s, 16, 64);
    s += __shfl_xor(s, 32, 64);
    if (quad == 0) atomicAdd(&Lsum[bq + p0 + w * 32 + mr * 16 + l16], s);
  }
#pragma unroll
  for (int mr = 0; mr < 2; ++mr)
#pragma unroll
    for (int ct = 0; ct < 4; ++ct)
#pragma unroll
      for (int r = 0; r < 4; ++r)
        atomicAdd(&Oacc[bC + (size_t)(ct * 16 + quad * 4 + r) * NPIX + p0 + w * 32 +
                        mr * 16 + l16],
                  oacc[mr][ct][r]);
}

// ---------------- merge: out[b][c][p] += Oacc[b][c][p] / Lsum[b][p] ----------------
__global__ __launch_bounds__(256) void merge_kernel(
    const float* __restrict__ Oacc, const float* __restrict__ Lsum,
    float* __restrict__ out) {
  int bid = blockIdx.x;
  int b = bid / 25, nt = bid % 25;
  int p = nt * 256 + threadIdx.x;
  float inv = 1.f / Lsum[(size_t)b * NPIX + p];
  size_t base = (size_t)b * CH * NPIX + p;
#pragma unroll
  for (int c = 0; c < 64; ++c)
    out[base + (size_t)c * NPIX] += Oacc[base + (size_t)c * NPIX] * inv;
}

extern "C" void kernel_launch(void* const* d_in, const int* in_sizes, int n_in,
                              void* d_out, int out_size, void* d_ws, size_t ws_size,
                              hipStream_t stream) {
  const float* x = (const float*)d_in[0];
  const float* w = (const float*)d_in[1];
  const float* bias = (const float*)d_in[2];
  float* out = (float*)d_out;
  char* ws = (char*)d_ws;
  // workspace layout (bytes) — max offset 29,556,736 (within proven ws size)
  unsigned short* Qbf = (unsigned short*)(ws);              // 3,276,800
  unsigned short* Qtbf = (unsigned short*)(ws + 3276800);   // 3,276,800
  unsigned short* VtTbf = (unsigned short*)(ws + 6553600);  // 3,276,800
  float* K32 = (float*)(ws + 9830400);                      // 6,553,600 (dead after gram)
  float* Qt32 = (float*)(ws + 16384000);                    // 6,553,600 (dead after gram)
  float* V32 = (float*)(ws + 22937600);                     // 6,553,600 (dead after chan)
  float* Pc = (float*)(ws + 29491200);                      // 65,536
  // aliases (live only after chan_apply):
  float* Oacc = (float*)(ws + 9830400);   // 6,553,600 over K32
  float* Lsum = (float*)(ws + 16384000);  // 102,400 over Qt32 head

  hipMemsetAsync(Pc, 0, 65536, stream);
  qkv_kernel<<<400, 256, 0, stream>>>(x, w, bias, Qbf, Qtbf, VtTbf, K32, Qt32, V32);
  gram_kernel<<<100, 256, 0, stream>>>(K32, Qt32, Pc);
  chan_apply<<<100, 256, 0, stream>>>(Pc, V32, out);
  hipMemsetAsync(ws + 9830400, 0, 6656000, stream);  // zero Oacc + Lsum
  flash_kernel<<<1000, 256, 0, stream>>>(Qbf, Qtbf, VtTbf, Oacc, Lsum);
  merge_kernel<<<100, 256, 0, stream>>>(Oacc, Lsum, out);
}

// Round 3
// 261.971 us; speedup vs baseline: 1.7380x; 1.1274x over previous
//
#include <hip/hip_runtime.h>
#include <stdint.h>

#define BATCH 4
#define CH 64
#define HW 80
#define NPIX 6400

typedef __attribute__((ext_vector_type(8))) short bf16x8;
typedef __attribute__((ext_vector_type(4))) float f32x4;

#define QSCALE 1.2011224087864498f   // sqrt(log2(e))
#define ESHIFT 115.41560327111707f   // 80 * log2(e)

static __device__ __forceinline__ unsigned short f2bf(float f) {
  union { float f; unsigned int u; } v; v.f = f;
  unsigned int u = v.u;
  return (unsigned short)((u + 0x7fffu + ((u >> 16) & 1u)) >> 16);
}
static __device__ __forceinline__ float bf2f(unsigned short h) {
  union { unsigned int u; float f; } v; v.u = ((unsigned int)h) << 16;
  return v.f;
}
// pack two floats to bf16x2 (round-half-up) — 5 VALU ops
static __device__ __forceinline__ unsigned int pack2(float a, float b) {
  union { float f; unsigned int u; } x, y; x.f = a; y.f = b;
  return ((x.u + 0x8000u) >> 16) | ((y.u + 0x8000u) & 0xffff0000u);
}
// fp32 -> (hi bf16 | lo bf16 << 16), hi+lo ≈ a to ~2^-17 rel
static __device__ __forceinline__ unsigned int split_pack(float a) {
  unsigned short hi = f2bf(a);
  union { unsigned int u; float f; } hf; hf.u = ((unsigned int)hi) << 16;
  unsigned short lo = f2bf(a - hf.f);
  return (unsigned int)hi | ((unsigned int)lo << 16);
}

// ---------------- QKV 1x1 conv ----------------
// Qtbf [b][p][c] bf16*QSCALE : row p = q[:, t(p)]  (flash queries AND keys)
// Vbf  [b][c][p] bf16        : values natural order (flash + chan)
// Kpk  [b][c][p] uint hi/lo  : gram A-side
// Qpk  [b][c][p] uint hi/lo  : gram B-side (read permuted in gram)
__global__ __launch_bounds__(256) void qkv_kernel(
    const float* __restrict__ x, const float* __restrict__ w,
    const float* __restrict__ bias, unsigned short* __restrict__ Qtbf,
    unsigned short* __restrict__ Vbf, unsigned int* __restrict__ Kpk,
    unsigned int* __restrict__ Qpk) {
  __shared__ float qs[64][65];
  int bid = blockIdx.x;
  int b = bid / 100, tile = bid % 100;
  int p0 = tile * 64;
  int t = threadIdx.x;
  int i = t & 63;
  int og = __builtin_amdgcn_readfirstlane(t >> 6);
  int p = p0 + i;
  const float* xb = x + (size_t)b * CH * NPIX + p;
  float xv[64];
#pragma unroll
  for (int c = 0; c < 64; ++c) xv[c] = xb[(size_t)c * NPIX];
  size_t bc = (size_t)b * CH * NPIX;
  for (int j = 0; j < 48; ++j) {
    int o = og * 48 + j;
    const float* wr = w + o * 64;
    float a = bias[o];
#pragma unroll
    for (int c = 0; c < 64; ++c) a += wr[c] * xv[c];
    int cc = o & 63;
    int kind = o >> 6;
    if (kind == 0) {
      qs[cc][i] = a;
      Qpk[bc + (size_t)cc * NPIX + p] = split_pack(a);
    } else if (kind == 1) {
      Kpk[bc + (size_t)cc * NPIX + p] = split_pack(a);
    } else {
      Vbf[bc + (size_t)cc * NPIX + p] = f2bf(a);
    }
  }
  __syncthreads();
  // restage q -> Qtbf rows (each row 128B contiguous, scaled by QSCALE)
  int j = t >> 2, g = t & 3;
  int pj = p0 + j;
  int tpj = (pj % HW) * HW + pj / HW;
  unsigned int pk8[8];
#pragma unroll
  for (int q4 = 0; q4 < 8; ++q4) {
    float a0 = qs[g * 16 + q4 * 2][j] * QSCALE;
    float a1 = qs[g * 16 + q4 * 2 + 1][j] * QSCALE;
    pk8[q4] = (unsigned int)f2bf(a0) | ((unsigned int)f2bf(a1) << 16);
  }
  unsigned short* dst = Qtbf + ((size_t)b * NPIX + tpj) * 64 + g * 16;
  uint4 w0 = {pk8[0], pk8[1], pk8[2], pk8[3]};
  uint4 w1 = {pk8[4], pk8[5], pk8[6], pk8[7]};
  *(uint4*)&dst[0] = w0;
  *(uint4*)&dst[8] = w1;
}

// ---------------- channel gram via split-bf16 MFMA ----------------
// M[c][c'] = sum_n K[c][n] * q[c'][t(n)]  (fp32-grade via hi/lo split, 3 MFMAs)
__global__ __launch_bounds__(256) void gram_kernel(
    const unsigned int* __restrict__ Kpk, const unsigned int* __restrict__ Qpk,
    float* __restrict__ Pc) {
  __shared__ unsigned short Ah[64 * 72], Al[64 * 72], Bh[64 * 72], Bl[64 * 72];
  int bid = blockIdx.x;
  int b = bid / 50, chunk = bid % 50;
  int t = threadIdx.x;
  int w = t >> 6, lane = t & 63;
  int quad = lane >> 4, l16 = lane & 15;
  size_t bc = (size_t)b * CH * NPIX;
  int row = t >> 2, g = t & 3;

  f32x4 acc[4];
#pragma unroll
  for (int ct = 0; ct < 4; ++ct) acc[ct] = (f32x4){0.f, 0.f, 0.f, 0.f};

  for (int sub = 0; sub < 2; ++sub) {
    int n0 = chunk * 128 + sub * 64;
    __syncthreads();
    // A-side: coalesced
    const unsigned int* ks = Kpk + bc + (size_t)row * NPIX + n0 + g * 16;
#pragma unroll
    for (int q4 = 0; q4 < 4; ++q4) {
      uint4 u = *(const uint4*)&ks[q4 * 4];
      uint2 h = {(u.x & 0xffffu) | ((u.y & 0xffffu) << 16),
                 (u.z & 0xffffu) | ((u.w & 0xffffu) << 16)};
      uint2 l = {(u.x >> 16) | (u.y & 0xffff0000u),
                 (u.z >> 16) | (u.w & 0xffff0000u)};
      *(uint2*)&Ah[row * 72 + g * 16 + q4 * 4] = h;
      *(uint2*)&Al[row * 72 + g * 16 + q4 * 4] = l;
    }
    // B-side: t-permuted scattered reads (L3-absorbed)
    unsigned int qu[16];
#pragma unroll
    for (int ii = 0; ii < 16; ++ii) {
      int n = n0 + g * 16 + ii;
      int tn = (n % HW) * HW + n / HW;
      qu[ii] = Qpk[bc + (size_t)row * NPIX + tn];
    }
#pragma unroll
    for (int q4 = 0; q4 < 4; ++q4) {
      uint2 h = {(qu[q4 * 4] & 0xffffu) | ((qu[q4 * 4 + 1] & 0xffffu) << 16),
                 (qu[q4 * 4 + 2] & 0xffffu) | ((qu[q4 * 4 + 3] & 0xffffu) << 16)};
      uint2 l = {(qu[q4 * 4] >> 16) | (qu[q4 * 4 + 1] & 0xffff0000u),
                 (qu[q4 * 4 + 2] >> 16) | (qu[q4 * 4 + 3] & 0xffff0000u)};
      *(uint2*)&Bh[row * 72 + g * 16 + q4 * 4] = h;
      *(uint2*)&Bl[row * 72 + g * 16 + q4 * 4] = l;
    }
    __syncthreads();
#pragma unroll
    for (int ks2 = 0; ks2 < 2; ++ks2) {
      bf16x8 ah = *(const bf16x8*)&Ah[(w * 16 + l16) * 72 + ks2 * 32 + quad * 8];
      bf16x8 al = *(const bf16x8*)&Al[(w * 16 + l16) * 72 + ks2 * 32 + quad * 8];
#pragma unroll
      for (int ct = 0; ct < 4; ++ct) {
        bf16x8 bh = *(const bf16x8*)&Bh[(ct * 16 + l16) * 72 + ks2 * 32 + quad * 8];
        bf16x8 bl = *(const bf16x8*)&Bl[(ct * 16 + l16) * 72 + ks2 * 32 + quad * 8];
        acc[ct] = __builtin_amdgcn_mfma_f32_16x16x32_bf16(ah, bh, acc[ct], 0, 0, 0);
        acc[ct] = __builtin_amdgcn_mfma_f32_16x16x32_bf16(ah, bl, acc[ct], 0, 0, 0);
        acc[ct] = __builtin_amdgcn_mfma_f32_16x16x32_bf16(al, bh, acc[ct], 0, 0, 0);
      }
    }
  }
#pragma unroll
  for (int ct = 0; ct < 4; ++ct)
#pragma unroll
    for (int r = 0; r < 4; ++r)
      atomicAdd(&Pc[((size_t)b * 64 + w * 16 + quad * 4 + r) * 64 + ct * 16 + l16],
                acc[ct][r]);
}

// ---------------- channel apply (softmax fused) ----------------
__global__ __launch_bounds__(256) void chan_apply(
    const float* __restrict__ Pc, const unsigned short* __restrict__ Vbf,
    float* __restrict__ out) {
  __shared__ float maT[64 * 64];  // [cp][c]
  int bid = blockIdx.x;
  int b = bid / 100, nt = bid % 100;
  int t = threadIdx.x;
  if (t < 64) {
    int c = t;
    const float* row = Pc + ((size_t)b * 64 + c) * 64;
    float v[64];
    float mx = -1e30f;
#pragma unroll
    for (int j = 0; j < 64; ++j) { v[j] = row[j]; mx = fmaxf(mx, v[j]); }
    float s = 0.f;
#pragma unroll
    for (int j = 0; j < 64; ++j) { v[j] = __expf(v[j] - mx); s += v[j]; }
    float inv = 1.f / s;
#pragma unroll
    for (int j = 0; j < 64; ++j) maT[j * 64 + c] = v[j] * inv;
  }
  __syncthreads();
  int lane = t & 63, ct = t >> 6;
  int n = nt * 64 + lane;
  size_t bc = (size_t)b * CH * NPIX;
  const unsigned short* vb = Vbf + bc + n;
  float acc[16];
#pragma unroll
  for (int j = 0; j < 16; ++j) acc[j] = 0.f;
  for (int cp = 0; cp < 64; ++cp) {
    float vv = bf2f(vb[(size_t)cp * NPIX]);
    const float* m = &maT[cp * 64 + ct * 16];
    f32x4 m0 = *(const f32x4*)&m[0];
    f32x4 m1 = *(const f32x4*)&m[4];
    f32x4 m2 = *(const f32x4*)&m[8];
    f32x4 m3 = *(const f32x4*)&m[12];
#pragma unroll
    for (int j = 0; j < 4; ++j) {
      acc[j] += m0[j] * vv;
      acc[4 + j] += m1[j] * vv;
      acc[8 + j] += m2[j] * vv;
      acc[12 + j] += m3[j] * vv;
    }
  }
#pragma unroll
  for (int j = 0; j < 16; ++j)
    out[bc + (size_t)(ct * 16 + j) * NPIX + n] = acc[j];
}

// ---------------- flash spatial attention, split-K ----------------
// keys = Qtbf rows m, values = Vbf[c][m] (t-involution reindex). Scores carry
// log2(e) from QSCALE^2 -> bare v_exp_f32 with fixed shift.
__global__ __launch_bounds__(256) void flash_kernel(
    const unsigned short* __restrict__ Qtbf, const unsigned short* __restrict__ Vbf,
    float* __restrict__ Oacc, float* __restrict__ Lsum) {
  __shared__ char smem[36864] __attribute__((aligned(128)));
  unsigned short* Ks = (unsigned short*)smem;            // [64][72]
  unsigned short* Vs = (unsigned short*)(smem + 9216);   // [64][72]
  unsigned short* Pb = (unsigned short*)(smem + 18432);  // [4 waves][32][72]

  int bid = blockIdx.x;
  int b = bid / 500;
  int rem = bid % 500;
  int qt = rem / 10, split = rem % 10;
  int p0 = qt * 128;
  int t = threadIdx.x;
  int w = t >> 6, lane = t & 63;
  int quad = lane >> 4, l16 = lane & 15;
  size_t bq = (size_t)b * NPIX;
  size_t bC = (size_t)b * CH * NPIX;

  bf16x8 aq[2][2];
#pragma unroll
  for (int mr = 0; mr < 2; ++mr)
#pragma unroll
    for (int ks = 0; ks < 2; ++ks)
      aq[mr][ks] = *(const bf16x8*)&Qtbf[(bq + p0 + w * 32 + mr * 16 + l16) * 64 +
                                         ks * 32 + quad * 8];

  f32x4 oacc[2][4];
#pragma unroll
  for (int mr = 0; mr < 2; ++mr)
#pragma unroll
    for (int ct = 0; ct < 4; ++ct) oacc[mr][ct] = (f32x4){0.f, 0.f, 0.f, 0.f};
  float psum[2] = {0.f, 0.f};

  const unsigned short* Kb = Qtbf + bq * 64;
  const unsigned short* Vb = Vbf + bC;
  int r0 = t >> 3, s0 = t & 7;
  int r1 = (t + 256) >> 3, s1 = t & 7;  // (t+256)&7 == t&7

  int kt0 = split * 10;
  uint4 kreg[2], vreg[2];
  {
    int n0 = kt0 * 64;
    kreg[0] = *(const uint4*)&Kb[(size_t)(n0 + r0) * 64 + s0 * 8];
    vreg[0] = *(const uint4*)&Vb[(size_t)r0 * NPIX + n0 + s0 * 8];
    kreg[1] = *(const uint4*)&Kb[(size_t)(n0 + r1) * 64 + s1 * 8];
    vreg[1] = *(const uint4*)&Vb[(size_t)r1 * NPIX + n0 + s1 * 8];
  }

  unsigned short* Pw = Pb + w * 32 * 72;
  for (int kt = kt0; kt < kt0 + 10; ++kt) {
    __syncthreads();  // prior iter's Ks/Vs reads done
    *(uint4*)&Ks[r0 * 72 + s0 * 8] = kreg[0];
    *(uint4*)&Vs[r0 * 72 + s0 * 8] = vreg[0];
    *(uint4*)&Ks[r1 * 72 + s1 * 8] = kreg[1];
    *(uint4*)&Vs[r1 * 72 + s1 * 8] = vreg[1];
    __syncthreads();
    if (kt + 1 < kt0 + 10) {
      int n1 = (kt + 1) * 64;
      kreg[0] = *(const uint4*)&Kb[(size_t)(n1 + r0) * 64 + s0 * 8];
      vreg[0] = *(const uint4*)&Vb[(size_t)r0 * NPIX + n1 + s0 * 8];
      kreg[1] = *(const uint4*)&Kb[(size_t)(n1 + r1) * 64 + s1 * 8];
      vreg[1] = *(const uint4*)&Vb[(size_t)r1 * NPIX + n1 + s1 * 8];
    }
    // S^T[k][m] per wave
    f32x4 sc[2][4];
#pragma unroll
    for (int mr = 0; mr < 2; ++mr)
#pragma unroll
      for (int ct = 0; ct < 4; ++ct) sc[mr][ct] = (f32x4){0.f, 0.f, 0.f, 0.f};
#pragma unroll
    for (int ks = 0; ks < 2; ++ks)
#pragma unroll
      for (int ct = 0; ct < 4; ++ct) {
        bf16x8 bk = *(const bf16x8*)&Ks[(ct * 16 + l16) * 72 + ks * 32 + quad * 8];
        sc[0][ct] = __builtin_amdgcn_mfma_f32_16x16x32_bf16(bk, aq[0][ks], sc[0][ct], 0, 0, 0);
        sc[1][ct] = __builtin_amdgcn_mfma_f32_16x16x32_bf16(bk, aq[1][ks], sc[1][ct], 0, 0, 0);
      }
    // exp2 + pack
#pragma unroll
    for (int mr = 0; mr < 2; ++mr)
#pragma unroll
      for (int ct = 0; ct < 4; ++ct) {
        float e0 = __builtin_amdgcn_exp2f(sc[mr][ct][0] - ESHIFT);
        float e1 = __builtin_amdgcn_exp2f(sc[mr][ct][1] - ESHIFT);
        float e2 = __builtin_amdgcn_exp2f(sc[mr][ct][2] - ESHIFT);
        float e3 = __builtin_amdgcn_exp2f(sc[mr][ct][3] - ESHIFT);
        psum[mr] += (e0 + e1) + (e2 + e3);
        uint2 pk = {pack2(e0, e1), pack2(e2, e3)};
        *(uint2*)&Pw[(mr * 16 + l16) * 72 + ct * 16 + quad * 4] = pk;
      }
    bf16x8 pf0[2], pf1[2];
#pragma unroll
    for (int ks = 0; ks < 2; ++ks) {
      pf0[ks] = *(const bf16x8*)&Pw[l16 * 72 + ks * 32 + quad * 8];
      pf1[ks] = *(const bf16x8*)&Pw[(16 + l16) * 72 + ks * 32 + quad * 8];
    }
#pragma unroll
    for (int ks = 0; ks < 2; ++ks)
#pragma unroll
      for (int ct = 0; ct < 4; ++ct) {
        bf16x8 vf = *(const bf16x8*)&Vs[(ct * 16 + l16) * 72 + ks * 32 + quad * 8];
        oacc[0][ct] = __builtin_amdgcn_mfma_f32_16x16x32_bf16(vf, pf0[ks], oacc[0][ct], 0, 0, 0);
        oacc[1][ct] = __builtin_amdgcn_mfma_f32_16x16x32_bf16(vf, pf1[ks], oacc[1][ct], 0, 0, 0);
      }
  }
#pragma unroll
  for (int mr = 0; mr < 2; ++mr) {
    float s = psum[mr];
    s += __shfl_xor(s, 16, 64);
    s += __shfl_xor(s, 32, 64);
    if (quad == 0) atomicAdd(&Lsum[bq + p0 + w * 32 + mr * 16 + l16], s);
  }
#pragma unroll
  for (int mr = 0; mr < 2; ++mr)
#pragma unroll
    for (int ct = 0; ct < 4; ++ct)
#pragma unroll
      for (int r = 0; r < 4; ++r)
        atomicAdd(&Oacc[bC + (size_t)(ct * 16 + quad * 4 + r) * NPIX + p0 + w * 32 +
                        mr * 16 + l16],
                  oacc[mr][ct][r]);
}

// ---------------- merge ----------------
__global__ __launch_bounds__(256) void merge_kernel(
    const float* __restrict__ Oacc, const float* __restrict__ Lsum,
    float* __restrict__ out) {
  int bid = blockIdx.x;
  int b = bid / 100, nt = bid % 100;
  int t = threadIdx.x;
  int lane = t & 63, w = t >> 6;
  int p = nt * 64 + lane;
  float inv = 1.f / Lsum[(size_t)b * NPIX + p];
  size_t base = (size_t)b * CH * NPIX + p;
#pragma unroll
  for (int j = 0; j < 16; ++j) {
    size_t off = base + (size_t)(w * 16 + j) * NPIX;
    out[off] += Oacc[off] * inv;
  }
}

extern "C" void kernel_launch(void* const* d_in, const int* in_sizes, int n_in,
                              void* d_out, int out_size, void* d_ws, size_t ws_size,
                              hipStream_t stream) {
  const float* x = (const float*)d_in[0];
  const float* w = (const float*)d_in[1];
  const float* bias = (const float*)d_in[2];
  float* out = (float*)d_out;
  char* ws = (char*)d_ws;
  unsigned short* Qtbf = (unsigned short*)(ws);             // 3,276,800
  unsigned short* Vbf = (unsigned short*)(ws + 3276800);    // 3,276,800
  unsigned int* Kpk = (unsigned int*)(ws + 6553600);        // 6,553,600
  unsigned int* Qpk = (unsigned int*)(ws + 13107200);       // 6,553,600
  float* Pc = (float*)(ws + 19660800);                      // 65,536
  float* Oacc = (float*)(ws + 19726336);                    // 6,553,600
  float* Lsum = (float*)(ws + 26279936);                    // 102,400 (end 26,382,336)

  hipMemsetAsync(ws + 19660800, 0, 6721536, stream);  // Pc + Oacc + Lsum
  qkv_kernel<<<400, 256, 0, stream>>>(x, w, bias, Qtbf, Vbf, Kpk, Qpk);
  gram_kernel<<<200, 256, 0, stream>>>(Kpk, Qpk, Pc);
  chan_apply<<<400, 256, 0, stream>>>(Pc, Vbf, out);
  flash_kernel<<<2000, 256, 0, stream>>>(Qtbf, Vbf, Oacc, Lsum);
  merge_kernel<<<400, 256, 0, stream>>>(Oacc, Lsum, out);
}

// Round 4
// 221.330 us; speedup vs baseline: 2.0571x; 1.1836x over previous
//
#include <hip/hip_runtime.h>
#include <stdint.h>

#define BATCH 4
#define CH 64
#define HW 80
#define NPIX 6400
#define SPLITS 3

typedef __attribute__((ext_vector_type(8))) short bf16x8;
typedef __attribute__((ext_vector_type(4))) float f32x4;

#define QSCALE 1.2011224087864498f   // sqrt(log2(e))
#define ESHIFT 115.41560327111707f   // 80 * log2(e)

static __device__ __forceinline__ unsigned short f2bf(float f) {
  union { float f; unsigned int u; } v; v.f = f;
  unsigned int u = v.u;
  return (unsigned short)((u + 0x7fffu + ((u >> 16) & 1u)) >> 16);
}
static __device__ __forceinline__ float bf2f(unsigned short h) {
  union { unsigned int u; float f; } v; v.u = ((unsigned int)h) << 16;
  return v.f;
}
// pack two floats to bf16x2 (round-half-up)
static __device__ __forceinline__ unsigned int pack2(float a, float b) {
  union { float f; unsigned int u; } x, y; x.f = a; y.f = b;
  return ((x.u + 0x8000u) >> 16) | ((y.u + 0x8000u) & 0xffff0000u);
}
// fp32 -> (hi bf16 | lo bf16 << 16)
static __device__ __forceinline__ unsigned int split_pack(float a) {
  unsigned short hi = f2bf(a);
  union { unsigned int u; float f; } hf; hf.u = ((unsigned int)hi) << 16;
  unsigned short lo = f2bf(a - hf.f);
  return (unsigned int)hi | ((unsigned int)lo << 16);
}

// ---------------- QKV 1x1 conv ----------------
__global__ __launch_bounds__(256) void qkv_kernel(
    const float* __restrict__ x, const float* __restrict__ w,
    const float* __restrict__ bias, unsigned short* __restrict__ Qtbf,
    unsigned short* __restrict__ Vbf, unsigned int* __restrict__ Kpk,
    unsigned int* __restrict__ Qpk) {
  __shared__ float qs[64][65];
  int bid = blockIdx.x;
  int b = bid / 100, tile = bid % 100;
  int p0 = tile * 64;
  int t = threadIdx.x;
  int i = t & 63;
  int og = __builtin_amdgcn_readfirstlane(t >> 6);
  int p = p0 + i;
  const float* xb = x + (size_t)b * CH * NPIX + p;
  float xv[64];
#pragma unroll
  for (int c = 0; c < 64; ++c) xv[c] = xb[(size_t)c * NPIX];
  size_t bc = (size_t)b * CH * NPIX;
  for (int j = 0; j < 48; ++j) {
    int o = og * 48 + j;
    const float* wr = w + o * 64;
    float a = bias[o];
#pragma unroll
    for (int c = 0; c < 64; ++c) a += wr[c] * xv[c];
    int cc = o & 63;
    int kind = o >> 6;
    if (kind == 0) {
      qs[cc][i] = a;
      Qpk[bc + (size_t)cc * NPIX + p] = split_pack(a);
    } else if (kind == 1) {
      Kpk[bc + (size_t)cc * NPIX + p] = split_pack(a);
    } else {
      Vbf[bc + (size_t)cc * NPIX + p] = f2bf(a);
    }
  }
  __syncthreads();
  // restage q -> Qtbf rows (row 128B contiguous, scaled by QSCALE)
  int j = t >> 2, g = t & 3;
  int pj = p0 + j;
  int tpj = (pj % HW) * HW + pj / HW;
  unsigned int pk8[8];
#pragma unroll
  for (int q4 = 0; q4 < 8; ++q4) {
    float a0 = qs[g * 16 + q4 * 2][j] * QSCALE;
    float a1 = qs[g * 16 + q4 * 2 + 1][j] * QSCALE;
    pk8[q4] = (unsigned int)f2bf(a0) | ((unsigned int)f2bf(a1) << 16);
  }
  unsigned short* dst = Qtbf + ((size_t)b * NPIX + tpj) * 64 + g * 16;
  uint4 w0 = {pk8[0], pk8[1], pk8[2], pk8[3]};
  uint4 w1 = {pk8[4], pk8[5], pk8[6], pk8[7]};
  *(uint4*)&dst[0] = w0;
  *(uint4*)&dst[8] = w1;
}

// ---------------- channel gram via split-bf16 MFMA ----------------
__global__ __launch_bounds__(256) void gram_kernel(
    const unsigned int* __restrict__ Kpk, const unsigned int* __restrict__ Qpk,
    float* __restrict__ Pc) {
  __shared__ unsigned short Ah[64 * 72], Al[64 * 72], Bh[64 * 72], Bl[64 * 72];
  int bid = blockIdx.x;
  int b = bid / 50, chunk = bid % 50;
  int t = threadIdx.x;
  int w = t >> 6, lane = t & 63;
  int quad = lane >> 4, l16 = lane & 15;
  size_t bc = (size_t)b * CH * NPIX;
  int row = t >> 2, g = t & 3;

  f32x4 acc[4];
#pragma unroll
  for (int ct = 0; ct < 4; ++ct) acc[ct] = (f32x4){0.f, 0.f, 0.f, 0.f};

  for (int sub = 0; sub < 2; ++sub) {
    int n0 = chunk * 128 + sub * 64;
    __syncthreads();
    const unsigned int* ks = Kpk + bc + (size_t)row * NPIX + n0 + g * 16;
#pragma unroll
    for (int q4 = 0; q4 < 4; ++q4) {
      uint4 u = *(const uint4*)&ks[q4 * 4];
      uint2 h = {(u.x & 0xffffu) | ((u.y & 0xffffu) << 16),
                 (u.z & 0xffffu) | ((u.w & 0xffffu) << 16)};
      uint2 l = {(u.x >> 16) | (u.y & 0xffff0000u),
                 (u.z >> 16) | (u.w & 0xffff0000u)};
      *(uint2*)&Ah[row * 72 + g * 16 + q4 * 4] = h;
      *(uint2*)&Al[row * 72 + g * 16 + q4 * 4] = l;
    }
    unsigned int qu[16];
#pragma unroll
    for (int ii = 0; ii < 16; ++ii) {
      int n = n0 + g * 16 + ii;
      int tn = (n % HW) * HW + n / HW;
      qu[ii] = Qpk[bc + (size_t)row * NPIX + tn];
    }
#pragma unroll
    for (int q4 = 0; q4 < 4; ++q4) {
      uint2 h = {(qu[q4 * 4] & 0xffffu) | ((qu[q4 * 4 + 1] & 0xffffu) << 16),
                 (qu[q4 * 4 + 2] & 0xffffu) | ((qu[q4 * 4 + 3] & 0xffffu) << 16)};
      uint2 l = {(qu[q4 * 4] >> 16) | (qu[q4 * 4 + 1] & 0xffff0000u),
                 (qu[q4 * 4 + 2] >> 16) | (qu[q4 * 4 + 3] & 0xffff0000u)};
      *(uint2*)&Bh[row * 72 + g * 16 + q4 * 4] = h;
      *(uint2*)&Bl[row * 72 + g * 16 + q4 * 4] = l;
    }
    __syncthreads();
#pragma unroll
    for (int ks2 = 0; ks2 < 2; ++ks2) {
      bf16x8 ah = *(const bf16x8*)&Ah[(w * 16 + l16) * 72 + ks2 * 32 + quad * 8];
      bf16x8 al = *(const bf16x8*)&Al[(w * 16 + l16) * 72 + ks2 * 32 + quad * 8];
#pragma unroll
      for (int ct = 0; ct < 4; ++ct) {
        bf16x8 bh = *(const bf16x8*)&Bh[(ct * 16 + l16) * 72 + ks2 * 32 + quad * 8];
        bf16x8 bl = *(const bf16x8*)&Bl[(ct * 16 + l16) * 72 + ks2 * 32 + quad * 8];
        acc[ct] = __builtin_amdgcn_mfma_f32_16x16x32_bf16(ah, bh, acc[ct], 0, 0, 0);
        acc[ct] = __builtin_amdgcn_mfma_f32_16x16x32_bf16(ah, bl, acc[ct], 0, 0, 0);
        acc[ct] = __builtin_amdgcn_mfma_f32_16x16x32_bf16(al, bh, acc[ct], 0, 0, 0);
      }
    }
  }
#pragma unroll
  for (int ct = 0; ct < 4; ++ct)
#pragma unroll
    for (int r = 0; r < 4; ++r)
      atomicAdd(&Pc[((size_t)b * 64 + w * 16 + quad * 4 + r) * 64 + ct * 16 + l16],
                acc[ct][r]);
}

// ---------------- flash spatial attention: split-K, no atomics, xor-swizzled LDS
__global__ __launch_bounds__(256) void flash_kernel(
    const unsigned short* __restrict__ Qtbf, const unsigned short* __restrict__ Vbf,
    float* __restrict__ Opart, float* __restrict__ Lpart) {
  __shared__ char smem[32768] __attribute__((aligned(128)));
  unsigned short* Ks = (unsigned short*)smem;            // [64][64] swizzled
  unsigned short* Vs = (unsigned short*)(smem + 8192);   // [64][64] swizzled
  unsigned short* Pb = (unsigned short*)(smem + 16384);  // [128][64] swizzled

  int bid = blockIdx.x;
  int b = bid / 150;
  int rem = bid % 150;
  int qt = rem / 3, split = rem % 3;
  int p0 = qt * 128;
  int t = threadIdx.x;
  int w = t >> 6, lane = t & 63;
  int quad = lane >> 4, l16 = lane & 15;
  int sw = l16 & 7;
  size_t bq = (size_t)b * NPIX;
  size_t bC = (size_t)b * CH * NPIX;

  bf16x8 aq[2][2];
#pragma unroll
  for (int mr = 0; mr < 2; ++mr)
#pragma unroll
    for (int ks = 0; ks < 2; ++ks)
      aq[mr][ks] = *(const bf16x8*)&Qtbf[(bq + p0 + w * 32 + mr * 16 + l16) * 64 +
                                         ks * 32 + quad * 8];

  f32x4 oacc[2][4];
#pragma unroll
  for (int mr = 0; mr < 2; ++mr)
#pragma unroll
    for (int ct = 0; ct < 4; ++ct) oacc[mr][ct] = (f32x4){0.f, 0.f, 0.f, 0.f};
  float psum[2] = {0.f, 0.f};

  const unsigned short* Kb = Qtbf + bq * 64;
  const unsigned short* Vb = Vbf + bC;
  int r0 = t >> 3, s0 = t & 7;  // r0 in [0,32)
  int r1 = r0 + 32;
  int wOff0 = r0 * 64 + ((s0 ^ (r0 & 7)) << 3);  // swizzled LDS dest (halves)
  int wOff1 = r1 * 64 + ((s0 ^ (r1 & 7)) << 3);

  int kt0 = split * 34;
  int ktend = kt0 + ((split == 2) ? 32 : 34);

  uint4 kreg0, kreg1, vreg0, vreg1;
  {
    int n0 = kt0 * 64;
    kreg0 = *(const uint4*)&Kb[(size_t)(n0 + r0) * 64 + s0 * 8];
    vreg0 = *(const uint4*)&Vb[(size_t)r0 * NPIX + n0 + s0 * 8];
    kreg1 = *(const uint4*)&Kb[(size_t)(n0 + r1) * 64 + s0 * 8];
    vreg1 = *(const uint4*)&Vb[(size_t)r1 * NPIX + n0 + s0 * 8];
  }

  unsigned short* Pw = Pb + w * 32 * 64;
  for (int kt = kt0; kt < ktend; ++kt) {
    __syncthreads();  // prior iter's LDS reads done
    *(uint4*)&Ks[wOff0] = kreg0;
    *(uint4*)&Vs[wOff0] = vreg0;
    *(uint4*)&Ks[wOff1] = kreg1;
    *(uint4*)&Vs[wOff1] = vreg1;
    __syncthreads();
    if (kt + 1 < ktend) {
      int n1 = (kt + 1) * 64;
      kreg0 = *(const uint4*)&Kb[(size_t)(n1 + r0) * 64 + s0 * 8];
      vreg0 = *(const uint4*)&Vb[(size_t)r0 * NPIX + n1 + s0 * 8];
      kreg1 = *(const uint4*)&Kb[(size_t)(n1 + r1) * 64 + s0 * 8];
      vreg1 = *(const uint4*)&Vb[(size_t)r1 * NPIX + n1 + s0 * 8];
    }
    // S^T[k][m]: C-layout row=key=ct*16+quad*4+r, col=query=l16
    f32x4 sc[2][4];
#pragma unroll
    for (int mr = 0; mr < 2; ++mr)
#pragma unroll
      for (int ct = 0; ct < 4; ++ct) sc[mr][ct] = (f32x4){0.f, 0.f, 0.f, 0.f};
#pragma unroll
    for (int ks = 0; ks < 2; ++ks)
#pragma unroll
      for (int ct = 0; ct < 4; ++ct) {
        bf16x8 bk = *(const bf16x8*)&Ks[(ct * 16 + l16) * 64 +
                                        (((ks * 4 + quad) ^ sw) << 3)];
        sc[0][ct] = __builtin_amdgcn_mfma_f32_16x16x32_bf16(bk, aq[0][ks], sc[0][ct], 0, 0, 0);
        sc[1][ct] = __builtin_amdgcn_mfma_f32_16x16x32_bf16(bk, aq[1][ks], sc[1][ct], 0, 0, 0);
      }
    // exp2 + pack -> P[m][k] (swizzled)
#pragma unroll
    for (int mr = 0; mr < 2; ++mr)
#pragma unroll
      for (int ct = 0; ct < 4; ++ct) {
        float e0 = __builtin_amdgcn_exp2f(sc[mr][ct][0] - ESHIFT);
        float e1 = __builtin_amdgcn_exp2f(sc[mr][ct][1] - ESHIFT);
        float e2 = __builtin_amdgcn_exp2f(sc[mr][ct][2] - ESHIFT);
        float e3 = __builtin_amdgcn_exp2f(sc[mr][ct][3] - ESHIFT);
        psum[mr] += (e0 + e1) + (e2 + e3);
        uint2 pk = {pack2(e0, e1), pack2(e2, e3)};
        *(uint2*)&Pw[(mr * 16 + l16) * 64 +
                     (((2 * ct + (quad >> 1)) ^ sw) << 3) + ((quad & 1) << 2)] = pk;
      }
    bf16x8 pf0[2], pf1[2];
#pragma unroll
    for (int ks = 0; ks < 2; ++ks) {
      pf0[ks] = *(const bf16x8*)&Pw[l16 * 64 + (((ks * 4 + quad) ^ sw) << 3)];
      pf1[ks] = *(const bf16x8*)&Pw[(16 + l16) * 64 + (((ks * 4 + quad) ^ sw) << 3)];
    }
#pragma unroll
    for (int ks = 0; ks < 2; ++ks)
#pragma unroll
      for (int ct = 0; ct < 4; ++ct) {
        bf16x8 vf = *(const bf16x8*)&Vs[(ct * 16 + l16) * 64 +
                                        (((ks * 4 + quad) ^ sw) << 3)];
        oacc[0][ct] = __builtin_amdgcn_mfma_f32_16x16x32_bf16(vf, pf0[ks], oacc[0][ct], 0, 0, 0);
        oacc[1][ct] = __builtin_amdgcn_mfma_f32_16x16x32_bf16(vf, pf1[ks], oacc[1][ct], 0, 0, 0);
      }
  }
  // epilogue: direct stores (no atomics)
  float* Op = Opart + (size_t)(split * BATCH + b) * CH * NPIX;
  int pcol = p0 + w * 32 + l16;
#pragma unroll
  for (int mr = 0; mr < 2; ++mr) {
    float s = psum[mr];
    s += __shfl_xor(s, 16, 64);
    s += __shfl_xor(s, 32, 64);
    if (quad == 0) Lpart[(size_t)(split * BATCH + b) * NPIX + pcol + mr * 16] = s;
  }
#pragma unroll
  for (int mr = 0; mr < 2; ++mr)
#pragma unroll
    for (int ct = 0; ct < 4; ++ct)
#pragma unroll
      for (int r = 0; r < 4; ++r)
        Op[(size_t)(ct * 16 + quad * 4 + r) * NPIX + pcol + mr * 16] = oacc[mr][ct][r];
}

// ---------------- finalize: out = chan_term + (sum_s Opart_s) / (sum_s Lpart_s)
__global__ __launch_bounds__(256) void finalize_kernel(
    const float* __restrict__ Pc, const unsigned short* __restrict__ Vbf,
    const float* __restrict__ Opart, const float* __restrict__ Lpart,
    float* __restrict__ out) {
  __shared__ float maT[64 * 64];  // [cp][c]
  int bid = blockIdx.x;
  int b = bid / 100, nt = bid % 100;
  int t = threadIdx.x;
  if (t < 64) {
    int c = t;
    const float* row = Pc + ((size_t)b * 64 + c) * 64;
    float v[64];
    float mx = -1e30f;
#pragma unroll
    for (int j = 0; j < 64; ++j) { v[j] = row[j]; mx = fmaxf(mx, v[j]); }
    float s = 0.f;
#pragma unroll
    for (int j = 0; j < 64; ++j) { v[j] = __expf(v[j] - mx); s += v[j]; }
    float inv = 1.f / s;
#pragma unroll
    for (int j = 0; j < 64; ++j) maT[j * 64 + c] = v[j] * inv;
  }
  __syncthreads();
  int lane = t & 63, ct = t >> 6;
  int n = nt * 64 + lane;
  size_t bc = (size_t)b * CH * NPIX;
  const unsigned short* vb = Vbf + bc + n;
  float acc[16];
#pragma unroll
  for (int j = 0; j < 16; ++j) acc[j] = 0.f;
  for (int cp = 0; cp < 64; ++cp) {
    float vv = bf2f(vb[(size_t)cp * NPIX]);
    const float* m = &maT[cp * 64 + ct * 16];
    f32x4 m0 = *(const f32x4*)&m[0];
    f32x4 m1 = *(const f32x4*)&m[4];
    f32x4 m2 = *(const f32x4*)&m[8];
    f32x4 m3 = *(const f32x4*)&m[12];
#pragma unroll
    for (int j = 0; j < 4; ++j) {
      acc[j] += m0[j] * vv;
      acc[4 + j] += m1[j] * vv;
      acc[8 + j] += m2[j] * vv;
      acc[12 + j] += m3[j] * vv;
    }
  }
  float lsum = Lpart[(size_t)(0 * BATCH + b) * NPIX + n] +
               Lpart[(size_t)(1 * BATCH + b) * NPIX + n] +
               Lpart[(size_t)(2 * BATCH + b) * NPIX + n];
  float inv = 1.f / lsum;
  const float* O0 = Opart + (size_t)(0 * BATCH + b) * CH * NPIX;
  const float* O1 = Opart + (size_t)(1 * BATCH + b) * CH * NPIX;
  const float* O2 = Opart + (size_t)(2 * BATCH + b) * CH * NPIX;
#pragma unroll
  for (int j = 0; j < 16; ++j) {
    size_t co = (size_t)(ct * 16 + j) * NPIX + n;
    float o = O0[co] + O1[co] + O2[co];
    out[bc + co] = acc[j] + o * inv;
  }
}

extern "C" void kernel_launch(void* const* d_in, const int* in_sizes, int n_in,
                              void* d_out, int out_size, void* d_ws, size_t ws_size,
                              hipStream_t stream) {
  const float* x = (const float*)d_in[0];
  const float* w = (const float*)d_in[1];
  const float* bias = (const float*)d_in[2];
  float* out = (float*)d_out;
  char* ws = (char*)d_ws;
  // layout (bytes):
  unsigned short* Qtbf = (unsigned short*)(ws);           // [0, 3276800)
  unsigned short* Vbf = (unsigned short*)(ws + 3276800);  // [3276800, 6553600)
  unsigned int* Kpk = (unsigned int*)(ws + 6553600);      // [6553600, 13107200) dead after gram
  unsigned int* Qpk = (unsigned int*)(ws + 13107200);     // [13107200, 19660800) dead after gram
  float* Opart = (float*)(ws + 6553600);                  // [6553600, 26214400) 3 splits, after gram
  float* Pc = (float*)(ws + 26214400);                    // [26214400, 26279936)
  float* Lpart = (float*)(ws + 26279936);                 // [26279936, 26587136)

  hipMemsetAsync(Pc, 0, 65536, stream);
  qkv_kernel<<<400, 256, 0, stream>>>(x, w, bias, Qtbf, Vbf, Kpk, Qpk);
  gram_kernel<<<200, 256, 0, stream>>>(Kpk, Qpk, Pc);
  flash_kernel<<<600, 256, 0, stream>>>(Qtbf, Vbf, Opart, Lpart);
  finalize_kernel<<<400, 256, 0, stream>>>(Pc, Vbf, Opart, Lpart, out);
}